// Round 2
// baseline (168394.153 us; speedup 1.0000x reference)
//
#include <hip/hip_runtime.h>
#include <hip/hip_bf16.h>

#define B_ 64
#define T_ 1024
#define U_ 256
#define NWG 256
#define NTHR 512

__device__ __forceinline__ float sigf(float x) { return 1.f / (1.f + __expf(-x)); }

// ---------------- S = Wq @ Wk^T ----------------
__global__ __launch_bounds__(256) void k_S(const float* __restrict__ Wq,
                                           const float* __restrict__ Wk,
                                           float* __restrict__ S) {
  int d = blockIdx.x, e = threadIdx.x;
  __shared__ float wq[256];
  wq[e] = Wq[d * 256 + e];
  __syncthreads();
  const float* wk = Wk + (size_t)e * 256;
  float acc = 0.f;
#pragma unroll 8
  for (int u = 0; u < 256; ++u) acc = fmaf(wq[u], wk[u], acc);
  S[d * 256 + e] = acc;
}

// ---------------- z_x precompute (unchanged from R1; correct+fast enough) ----------------
template <bool ZX32>
__global__ __launch_bounds__(256) void k_zx(const float* __restrict__ x,
                                            const float* __restrict__ ker,
                                            float* __restrict__ zxf,
                                            __hip_bfloat16* __restrict__ zxh) {
  int tid = threadIdx.x;
  int r0 = blockIdx.x * 64;
  int c0 = blockIdx.y * 128;
  int g = blockIdx.z;
  int tr = tid >> 5;
  int tc = tid & 31;
  __shared__ float xs[64][17];
  __shared__ float wt[16][132];
  float4 acc[8];
#pragma unroll
  for (int r = 0; r < 8; ++r) acc[r] = make_float4(0.f, 0.f, 0.f, 0.f);

  for (int kc = 0; kc < 16; ++kc) {
    int k0 = kc * 16;
    {
      int row = tid >> 2, q4 = tid & 3;
      float4 v = *(const float4*)&x[(size_t)(r0 + row) * 256 + k0 + q4 * 4];
      xs[row][q4 * 4 + 0] = v.x; xs[row][q4 * 4 + 1] = v.y;
      xs[row][q4 * 4 + 2] = v.z; xs[row][q4 * 4 + 3] = v.w;
    }
#pragma unroll
    for (int it = 0; it < 2; ++it) {
      int i = tid + it * 256;
      int kk = i >> 5, cq = i & 31;
      float4 v = *(const float4*)&ker[((size_t)g * 256 + k0 + kk) * 256 + c0 + cq * 4];
      wt[kk][cq * 4 + 0] = v.x; wt[kk][cq * 4 + 1] = v.y;
      wt[kk][cq * 4 + 2] = v.z; wt[kk][cq * 4 + 3] = v.w;
    }
    __syncthreads();
#pragma unroll
    for (int kk = 0; kk < 16; ++kk) {
      float4 wc = *(const float4*)&wt[kk][tc * 4];
#pragma unroll
      for (int r = 0; r < 8; ++r) {
        float xr = xs[tr * 8 + r][kk];
        acc[r].x = fmaf(xr, wc.x, acc[r].x);
        acc[r].y = fmaf(xr, wc.y, acc[r].y);
        acc[r].z = fmaf(xr, wc.z, acc[r].z);
        acc[r].w = fmaf(xr, wc.w, acc[r].w);
      }
    }
    __syncthreads();
  }
#pragma unroll
  for (int r = 0; r < 8; ++r) {
    size_t bt = (size_t)(r0 + tr * 8 + r);
    size_t zi = (bt * 4 + g) * 256 + c0 + tc * 4;
    if (ZX32) {
      *(float4*)&zxf[zi] = acc[r];
    } else {
      zxh[zi + 0] = __float2bfloat16(acc[r].x);
      zxh[zi + 1] = __float2bfloat16(acc[r].y);
      zxh[zi + 2] = __float2bfloat16(acc[r].z);
      zxh[zi + 3] = __float2bfloat16(acc[r].w);
    }
  }
}

// ---------------- device-wide barrier (monotone counter, AGENT scope) ----------------
__device__ __forceinline__ void gridbar(unsigned* bar, unsigned target) {
  __threadfence();           // publish this thread's stores (wb)
  __syncthreads();
  if (threadIdx.x == 0) {
    __hip_atomic_fetch_add(bar, 1u, __ATOMIC_ACQ_REL, __HIP_MEMORY_SCOPE_AGENT);
    while (__hip_atomic_load(bar, __ATOMIC_ACQUIRE, __HIP_MEMORY_SCOPE_AGENT) < target) {
      __builtin_amdgcn_s_sleep(2);
    }
  }
  __syncthreads();
  __threadfence();           // invalidate stale cached lines before consuming remote data
}

// ---------------- persistent cross-CU step kernel ----------------
// 256 WGs = 16 batch-groups (4 batches) x 16 u-slices (16 u's). 512 threads.
template <bool ZX32>
__global__ __launch_bounds__(NTHR) void k_loop(
    const float* __restrict__ S, const float* __restrict__ RA,
    const float* __restrict__ Wv, const float* __restrict__ zxf,
    const __hip_bfloat16* __restrict__ zxh, const float* __restrict__ bias,
    float* __restrict__ out, float* __restrict__ Hg, float* __restrict__ Tg,
    float* __restrict__ Vg, unsigned* __restrict__ bar) {
  const int tid = threadIdx.x;
  const int wg = blockIdx.x;
  const int us = wg & 15;        // same us -> same XCD (wg%8 fixed) -> shared L2 slice
  const int bg = wg >> 4;
  const int bg4 = bg * 4;
  const int uo0 = us * 16;

  __shared__ float hring[4][4][260];
  __shared__ float tring[4][4][260];
  __shared__ float vring[4][4][260];
  __shared__ float eT[1024][4];
  __shared__ float zpart[4][2][4][16];
  __shared__ float zf[4][4][16];
  __shared__ float scl[4][16];
  __shared__ float atl[4][16];
  __shared__ float bsl[4][16];

  for (int i = tid; i < 4 * 4 * 260; i += NTHR) {
    ((float*)hring)[i] = 0.f;
    ((float*)tring)[i] = 0.f;
    ((float*)vring)[i] = 0.f;
  }
  if (tid < 64) bsl[tid >> 4][tid & 15] = bias[(tid >> 4) * 256 + uo0 + (tid & 15)];
  float creg = 0.f;  // cell state for tid<64: (b = tid>>4, u = tid&15)
  __syncthreads();

  unsigned tgt = 0;

  for (int t = 0; t < T_; ++t) {
    const int slot = (t + 3) & 3;  // ring slot of h_{t-1}

    // ---- P1a: gather h_new (= h_{t-1}) full, 4 batches ----
    {
      int bl = tid >> 7, d = (tid & 127) * 2;
      float2 hv = *(const float2*)&Hg[(bg4 + bl) * 256 + d];
      hring[slot][bl][d] = hv.x;
      hring[slot][bl][d + 1] = hv.y;
    }
    // ---- P1b: prefetch zx for this step (consumed in P2 combine) ----
    float zxv = 0.f;
    if (tid < 256) {
      int bl = tid >> 6, g = (tid >> 4) & 3, uu = tid & 15;
      size_t zi = (((size_t)(bg4 + bl) * 1024 + t) * 4 + g) * 256 + uo0 + uu;
      zxv = ZX32 ? zxf[zi] : __bfloat162float(zxh[zi]);
    }
    __syncthreads();

    // ---- P1c: t_new/v_new column slices: 128 outputs x 4 partial threads ----
    {
      int o128 = tid >> 2, p = tid & 3;
      int mat = o128 >> 6, bl = (o128 >> 4) & 3, uu = o128 & 15;
      const float* W = mat ? Wv : S;
      const float* hr = &hring[slot][bl][0];
      int col = uo0 + uu;
      float acc = 0.f;
#pragma unroll 8
      for (int it = 0; it < 64; ++it) {
        int d = p * 64 + it;
        acc = fmaf(hr[d], W[(size_t)d * 256 + col], acc);
      }
      acc += __shfl_xor(acc, 1);
      acc += __shfl_xor(acc, 2);
      if (p == 0) (mat ? Vg : Tg)[(bg4 + bl) * 256 + col] = acc;
    }
    tgt += NWG; gridbar(bar, tgt);  // ---- sync A ----

    // ---- P2a: gather t_new/v_new full into rings ----
    {
      int half = tid >> 8, bl = (tid >> 6) & 3, d = (tid & 63) * 4;
      const float* src = half ? Vg : Tg;
      float4 v4 = *(const float4*)&src[(bg4 + bl) * 256 + d];
      float* dst = half ? &vring[slot][bl][d] : &tring[slot][bl][d];
      *(float4*)dst = v4;
    }
    __syncthreads();

    // ---- P2b: scores: 64 dots (b,q,k) x 8 partials ----
    {
      int dt = tid >> 3, p8 = tid & 7;
      int bl = dt >> 4, q = (dt >> 2) & 3, k = dt & 3;
      int sq = (t - 1 - q) & 3, sk = (t - 1 - k) & 3;
      const float* tr = &tring[sq][bl][0];
      const float* hr = &hring[sk][bl][0];
      float s = 0.f;
#pragma unroll
      for (int kk = 0; kk < 8; ++kk) {
        int d0 = (kk * 8 + p8) * 4;
        float4 a4 = *(const float4*)&tr[d0];
        float4 b4 = *(const float4*)&hr[d0];
        s += a4.x * b4.x + a4.y * b4.y + a4.z * b4.z + a4.w * b4.w;
      }
      s += __shfl_xor(s, 1); s += __shfl_xor(s, 2); s += __shfl_xor(s, 4);
      if (p8 == 0) scl[bl][q * 4 + k] = s * 0.0625f;
    }
    __syncthreads();

    // ---- P2c: softmax rows ----
    if (tid < 16) {
      int bl = tid >> 2, q = tid & 3;
      float s0 = scl[bl][q * 4 + 0], s1 = scl[bl][q * 4 + 1];
      float s2 = scl[bl][q * 4 + 2], s3 = scl[bl][q * 4 + 3];
      float mx = fmaxf(fmaxf(s0, s1), fmaxf(s2, s3));
      float e0 = __expf(s0 - mx), e1 = __expf(s1 - mx);
      float e2 = __expf(s2 - mx), e3 = __expf(s3 - mx);
      float inv = 1.f / (e0 + e1 + e2 + e3);
      atl[bl][q * 4 + 0] = e0 * inv; atl[bl][q * 4 + 1] = e1 * inv;
      atl[bl][q * 4 + 2] = e2 * inv; atl[bl][q * 4 + 3] = e3 * inv;
    }
    __syncthreads();

    // ---- P2d: e = attn @ v, stored transposed eT[a][b] ----
    {
      int bl = tid >> 7, q = (tid >> 5) & 3, mb = tid & 31;
      float a0 = atl[bl][q * 4 + 0], a1 = atl[bl][q * 4 + 1];
      float a2 = atl[bl][q * 4 + 2], a3 = atl[bl][q * 4 + 3];
      int s0 = (t - 1) & 3, s1 = (t - 2) & 3, s2 = (t - 3) & 3, s3 = (t - 4) & 3;
#pragma unroll
      for (int j = 0; j < 8; ++j) {
        int m = mb + 32 * j;
        float ev = a0 * vring[s0][bl][m] + a1 * vring[s1][bl][m] +
                   a2 * vring[s2][bl][m] + a3 * vring[s3][bl][m];
        eT[q * 256 + m][bl] = ev;
      }
    }
    __syncthreads();

    // ---- P2e: z_rec slice: wave (g, a-half); lane (aa16, uq4) ----
    {
      int w = tid >> 6, l = tid & 63;
      int g = w & 3, ah = w >> 2;
      int aa = l >> 2, uq = l & 3;
      float4 ac0 = {0, 0, 0, 0}, ac1 = {0, 0, 0, 0}, ac2 = {0, 0, 0, 0}, ac3 = {0, 0, 0, 0};
      const float* rap = RA + ((size_t)g * 1024 + ah * 512 + aa) * 256 + uo0 + uq * 4;
      const float* ep = &eT[ah * 512 + aa][0];
#pragma unroll 4
      for (int it = 0; it < 32; ++it) {
        float4 e4 = *(const float4*)(ep + it * 64);          // eT[a][0..3]
        float4 r = *(const float4*)(rap + (size_t)it * 4096); // RA row a, 4 u's
        ac0.x = fmaf(e4.x, r.x, ac0.x); ac0.y = fmaf(e4.x, r.y, ac0.y);
        ac0.z = fmaf(e4.x, r.z, ac0.z); ac0.w = fmaf(e4.x, r.w, ac0.w);
        ac1.x = fmaf(e4.y, r.x, ac1.x); ac1.y = fmaf(e4.y, r.y, ac1.y);
        ac1.z = fmaf(e4.y, r.z, ac1.z); ac1.w = fmaf(e4.y, r.w, ac1.w);
        ac2.x = fmaf(e4.z, r.x, ac2.x); ac2.y = fmaf(e4.z, r.y, ac2.y);
        ac2.z = fmaf(e4.z, r.z, ac2.z); ac2.w = fmaf(e4.z, r.w, ac2.w);
        ac3.x = fmaf(e4.w, r.x, ac3.x); ac3.y = fmaf(e4.w, r.y, ac3.y);
        ac3.z = fmaf(e4.w, r.z, ac3.z); ac3.w = fmaf(e4.w, r.w, ac3.w);
      }
#pragma unroll
      for (int mask = 4; mask <= 32; mask <<= 1) {
        ac0.x += __shfl_xor(ac0.x, mask); ac0.y += __shfl_xor(ac0.y, mask);
        ac0.z += __shfl_xor(ac0.z, mask); ac0.w += __shfl_xor(ac0.w, mask);
        ac1.x += __shfl_xor(ac1.x, mask); ac1.y += __shfl_xor(ac1.y, mask);
        ac1.z += __shfl_xor(ac1.z, mask); ac1.w += __shfl_xor(ac1.w, mask);
        ac2.x += __shfl_xor(ac2.x, mask); ac2.y += __shfl_xor(ac2.y, mask);
        ac2.z += __shfl_xor(ac2.z, mask); ac2.w += __shfl_xor(ac2.w, mask);
        ac3.x += __shfl_xor(ac3.x, mask); ac3.y += __shfl_xor(ac3.y, mask);
        ac3.z += __shfl_xor(ac3.z, mask); ac3.w += __shfl_xor(ac3.w, mask);
      }
      if (l < 4) {
        *(float4*)&zpart[g][ah][0][l * 4] = ac0;
        *(float4*)&zpart[g][ah][1][l * 4] = ac1;
        *(float4*)&zpart[g][ah][2][l * 4] = ac2;
        *(float4*)&zpart[g][ah][3][l * 4] = ac3;
      }
    }
    __syncthreads();

    // ---- P2f: combine z ----
    if (tid < 256) {
      int bl = tid >> 6, g = (tid >> 4) & 3, uu = tid & 15;
      zf[bl][g][uu] = zpart[g][0][bl][uu] + zpart[g][1][bl][uu] + zxv + bsl[g][uu];
    }
    __syncthreads();

    // ---- P2g: gates + state + writes ----
    if (tid < 64) {
      int bl = tid >> 4, uu = tid & 15;
      float fg = sigf(zf[bl][0][uu]);
      float ig = sigf(zf[bl][1][uu]);
      float og = sigf(zf[bl][2][uu]);
      float ch = tanhf(zf[bl][3][uu]);
      creg = fmaf(fg, creg, ig * ch);
      float h = og * tanhf(creg);
      Hg[(bg4 + bl) * 256 + uo0 + uu] = h;
      out[((size_t)(bg4 + bl) * 1024 + t) * 256 + uo0 + uu] = h;
    }
    tgt += NWG; gridbar(bar, tgt);  // ---- sync B ----
  }
}

extern "C" void kernel_launch(void* const* d_in, const int* in_sizes, int n_in,
                              void* d_out, int out_size, void* d_ws, size_t ws_size,
                              hipStream_t stream) {
  const float* x    = (const float*)d_in[0];
  const float* ker  = (const float*)d_in[1];
  const float* ra   = (const float*)d_in[2];
  const float* bias = (const float*)d_in[3];
  const float* wq   = (const float*)d_in[4];
  const float* wk   = (const float*)d_in[5];
  const float* wv   = (const float*)d_in[6];
  float* out = (float*)d_out;

  char* ws = (char*)d_ws;
  unsigned* bar = (unsigned*)ws;                    // [0,4)
  float* Hg = (float*)(ws + 4096);                  // 64 KB
  float* Tg = (float*)(ws + 4096 + 65536);          // 64 KB
  float* Vg = (float*)(ws + 4096 + 131072);         // 64 KB
  float* S  = (float*)(ws + 4096 + 196608);         // 256 KB
  const size_t ZOFF = 1u << 20;
  float* zxf = (float*)(ws + ZOFF);
  __hip_bfloat16* zxh = (__hip_bfloat16*)(ws + ZOFF);

  bool zx32 = (ws_size >= ZOFF + (size_t)B_ * T_ * 4 * U_ * 4);

  hipMemsetAsync(ws, 0, 4096 + 196608, stream);     // bar + H/T/V (S overwritten by k_S)
  k_S<<<256, 256, 0, stream>>>(wq, wk, S);
  if (zx32) {
    k_zx<true><<<dim3(1024, 2, 4), 256, 0, stream>>>(x, ker, zxf, zxh);
    k_loop<true><<<NWG, NTHR, 0, stream>>>(S, ra, wv, zxf, zxh, bias, out, Hg, Tg, Vg, bar);
  } else {
    k_zx<false><<<dim3(1024, 2, 4), 256, 0, stream>>>(x, ker, zxf, zxh);
    k_loop<false><<<NWG, NTHR, 0, stream>>>(S, ra, wv, zxf, zxh, bias, out, Hg, Tg, Vg, bar);
  }
}

// Round 6
// 154794.019 us; speedup vs baseline: 1.0879x; 1.0879x over previous
//
#include <hip/hip_runtime.h>
#include <hip/hip_bf16.h>

#define B_ 64
#define T_ 1024
#define U_ 256

typedef __attribute__((ext_vector_type(8))) __bf16 bf16x8;
typedef __attribute__((ext_vector_type(4))) float f32x4;

__device__ __forceinline__ float sigf(float x) { return 1.f / (1.f + __expf(-x)); }

// ring layout: slot stride 2156 floats, row stride 268 floats
#define RIDX(s, b, d) ((s) * 2156 + (b) * 268 + (d))

// ---------------- S = Wq @ Wk^T ----------------
__global__ __launch_bounds__(256) void k_S(const float* __restrict__ Wq,
                                           const float* __restrict__ Wk,
                                           float* __restrict__ S) {
  int d = blockIdx.x, e = threadIdx.x;
  __shared__ float wq[256];
  wq[e] = Wq[d * 256 + e];
  __syncthreads();
  const float* wk = Wk + (size_t)e * 256;
  float acc = 0.f;
#pragma unroll 8
  for (int u = 0; u < 256; ++u) acc = fmaf(wq[u], wk[u], acc);
  S[d * 256 + e] = acc;
}

// ---------------- z_x precompute (proven R1/R2) ----------------
template <bool ZX32>
__global__ __launch_bounds__(256) void k_zx(const float* __restrict__ x,
                                            const float* __restrict__ ker,
                                            float* __restrict__ zxf,
                                            __hip_bfloat16* __restrict__ zxh) {
  int tid = threadIdx.x;
  int r0 = blockIdx.x * 64;
  int c0 = blockIdx.y * 128;
  int g = blockIdx.z;
  int tr = tid >> 5;
  int tc = tid & 31;
  __shared__ float xs[64][17];
  __shared__ float wt[16][132];
  float4 acc[8];
#pragma unroll
  for (int r = 0; r < 8; ++r) acc[r] = make_float4(0.f, 0.f, 0.f, 0.f);

  for (int kc = 0; kc < 16; ++kc) {
    int k0 = kc * 16;
    {
      int row = tid >> 2, q4 = tid & 3;
      float4 v = *(const float4*)&x[(size_t)(r0 + row) * 256 + k0 + q4 * 4];
      xs[row][q4 * 4 + 0] = v.x; xs[row][q4 * 4 + 1] = v.y;
      xs[row][q4 * 4 + 2] = v.z; xs[row][q4 * 4 + 3] = v.w;
    }
#pragma unroll
    for (int it = 0; it < 2; ++it) {
      int i = tid + it * 256;
      int kk = i >> 5, cq = i & 31;
      float4 v = *(const float4*)&ker[((size_t)g * 256 + k0 + kk) * 256 + c0 + cq * 4];
      wt[kk][cq * 4 + 0] = v.x; wt[kk][cq * 4 + 1] = v.y;
      wt[kk][cq * 4 + 2] = v.z; wt[kk][cq * 4 + 3] = v.w;
    }
    __syncthreads();
#pragma unroll
    for (int kk = 0; kk < 16; ++kk) {
      float4 wc = *(const float4*)&wt[kk][tc * 4];
#pragma unroll
      for (int r = 0; r < 8; ++r) {
        float xr = xs[tr * 8 + r][kk];
        acc[r].x = fmaf(xr, wc.x, acc[r].x);
        acc[r].y = fmaf(xr, wc.y, acc[r].y);
        acc[r].z = fmaf(xr, wc.z, acc[r].z);
        acc[r].w = fmaf(xr, wc.w, acc[r].w);
      }
    }
    __syncthreads();
  }
#pragma unroll
  for (int r = 0; r < 8; ++r) {
    size_t bt = (size_t)(r0 + tr * 8 + r);
    size_t zi = (bt * 4 + g) * 256 + c0 + tc * 4;
    if (ZX32) {
      *(float4*)&zxf[zi] = acc[r];
    } else {
      zxh[zi + 0] = __float2bfloat16(acc[r].x);
      zxh[zi + 1] = __float2bfloat16(acc[r].y);
      zxh[zi + 2] = __float2bfloat16(acc[r].z);
      zxh[zi + 3] = __float2bfloat16(acc[r].w);
    }
  }
}

// ---------------- group-local flag barrier, R2-proven fence discipline ----------------
// Per-thread __threadfence() on BOTH sides (publish / invalidate) — placement-
// independent cross-XCD correctness (R2 empirically validated this discipline
// with groups spanning XCDs). Flag protocol avoids R2's 256-way single-counter
// contention. 32 WGs per group; leader = us==0, wave-parallel flag scan.
__device__ __forceinline__ void xbar(unsigned* flg, unsigned* go, int us, unsigned ep) {
  __threadfence();   // every thread: drain stores + write back to coherence point
  __syncthreads();
  if (us == 0) {
    if (threadIdx.x < 32) {
      if (threadIdx.x == 0)
        __hip_atomic_store(&flg[0], ep, __ATOMIC_RELEASE, __HIP_MEMORY_SCOPE_AGENT);
      while (__hip_atomic_load(&flg[threadIdx.x], __ATOMIC_ACQUIRE, __HIP_MEMORY_SCOPE_AGENT) != ep)
        __builtin_amdgcn_s_sleep(1);
      if (threadIdx.x == 0)
        __hip_atomic_store(go, ep, __ATOMIC_RELEASE, __HIP_MEMORY_SCOPE_AGENT);
    }
  } else if (threadIdx.x == 0) {
    __hip_atomic_store(&flg[us], ep, __ATOMIC_RELEASE, __HIP_MEMORY_SCOPE_AGENT);
    while (__hip_atomic_load(go, __ATOMIC_ACQUIRE, __HIP_MEMORY_SCOPE_AGENT) != ep)
      __builtin_amdgcn_s_sleep(1);
  }
  __syncthreads();
  __threadfence();   // every thread: invalidate stale cached lines before remote reads
}

// ---------------- persistent step kernel ----------------
// 256 WGs = 8 groups (8 batches) x 32 u-slices (8 u's). 512 thr.
template <bool ZX32>
__global__ __launch_bounds__(512) void k_loop(
    const float* __restrict__ Sg, const float* __restrict__ RA,
    const float* __restrict__ Wvg, const float* __restrict__ zxf,
    const __hip_bfloat16* __restrict__ zxh, const float* __restrict__ bias,
    float* __restrict__ out, float* __restrict__ Hg, float* __restrict__ Tg,
    float* __restrict__ Vg, unsigned* __restrict__ bar) {
  const int tid = threadIdx.x;
  const int wg = blockIdx.x;
  const int grp = wg & 7;        // XCD-pure under round-robin (perf heuristic only)
  const int us = wg >> 3;        // 0..31 u-slice
  const int uo0 = us * 8;
  const int l = tid & 63;
  const int w = tid >> 6;        // wave 0..7

  unsigned* flg = bar + grp * 32;
  unsigned* go = bar + 512 + grp * 16;

  __shared__ float hring[4 * 2156];
  __shared__ float tring[4 * 2156];
  __shared__ float vring[4 * 2156];
  __shared__ float S_l[256][8];
  __shared__ float Wv_l[256][8];
  __shared__ float zsc[8][64][8];
  __shared__ float zf[8][32];
  __shared__ float scl[8][16];
  __shared__ float attn[8][4][4];
  __shared__ float bsl[4][8];

  for (int i = tid; i < 4 * 2156; i += 512) {
    hring[i] = 0.f; tring[i] = 0.f; vring[i] = 0.f;
  }
  for (int i = tid; i < 2048; i += 512) {
    int d = i >> 3, uu = i & 7;
    S_l[d][uu] = Sg[d * 256 + uo0 + uu];
    Wv_l[d][uu] = Wvg[d * 256 + uo0 + uu];
  }
  if (tid < 32) bsl[tid >> 3][tid & 7] = bias[(tid >> 3) * 256 + uo0 + (tid & 7)];

  // ---- RA B-frag preload (once): wave w owns K-chunk a in [w*128, w*128+128) ----
  bf16x8 bfrag[4][2];
  {
    const int kg = l >> 4, n16 = l & 15;
#pragma unroll
    for (int f = 0; f < 4; ++f)
#pragma unroll
      for (int nh = 0; nh < 2; ++nh) {
        int n = nh * 16 + n16, g = n >> 3, uu = n & 7;
#pragma unroll
        for (int j = 0; j < 8; ++j) {
          int a = w * 128 + f * 32 + kg * 8 + j;
          bfrag[f][nh][j] = (__bf16)RA[((size_t)g * 1024 + a) * 256 + uo0 + uu];
        }
      }
  }
  float creg = 0.f;  // cell state: tid<64 owns (b=tid>>3, u=uo0+(tid&7))
  __syncthreads();

  for (int t = 0; t < T_; ++t) {
    const int sN = (t + 3) & 3;  // ring slot of h_{t-1}

    // ---- A1: gather h_{t-1} (wave = batch, lane = float4 of 256) ----
    {
      int d = l * 4;
      float4 hv = *(const float4*)&Hg[((grp * 8 + w) << 8) + d];
      *(float4*)&hring[RIDX(sN, w, d)] = hv;
    }
    // ---- A2: zx prefetch for combine role ----
    const int cb = tid >> 5, cn = tid & 31;
    float zxv = 0.f;
    if (tid < 256) {
      int g = cn >> 3, uu = cn & 7;
      size_t zi = (((size_t)(grp * 8 + cb) * 1024 + t) * 4 + g) * 256 + uo0 + uu;
      zxv = ZX32 ? zxf[zi] : __bfloat162float(zxh[zi]);
    }
    __syncthreads();

    // ---- A3: t_new/v_new u-slices: wave = batch, lane = (uu, p) ----
    {
      int uu = l >> 3, p = l & 7;
      const float* hb = &hring[RIDX(sN, w, 0)];
      float at = 0.f, av = 0.f;
#pragma unroll 8
      for (int it = 0; it < 32; ++it) {
        int d = it * 8 + p;
        float hd = hb[d];
        at = fmaf(hd, S_l[d][uu], at);
        av = fmaf(hd, Wv_l[d][uu], av);
      }
      at += __shfl_xor(at, 1); at += __shfl_xor(at, 2); at += __shfl_xor(at, 4);
      av += __shfl_xor(av, 1); av += __shfl_xor(av, 2); av += __shfl_xor(av, 4);
      if (p == 0) {
        int gi = ((grp * 8 + w) << 8) + uo0 + uu;
        Tg[gi] = at;
        Vg[gi] = av;
      }
    }
    xbar(flg, go, us, 2 * t + 1);  // ---- sync A ----

    // ---- B1: gather full t_new/v_new ----
    {
      int d = l * 4;
      int gi = ((grp * 8 + w) << 8) + d;
      float4 tv = *(const float4*)&Tg[gi];
      float4 vv = *(const float4*)&Vg[gi];
      *(float4*)&tring[RIDX(sN, w, d)] = tv;
      *(float4*)&vring[RIDX(sN, w, d)] = vv;
    }
    __syncthreads();

    // ---- B2: scores: wave = batch, lane = (qk, p) ----
    {
      int qk = l >> 2, p = l & 3;
      int q = qk >> 2, k = qk & 3;
      const float* tq = &tring[RIDX((t - 1 - q) & 3, w, 0)];
      const float* hk = &hring[RIDX((t - 1 - k) & 3, w, 0)];
      float s = 0.f;
#pragma unroll
      for (int it = 0; it < 16; ++it) {
        int d = it * 16 + p * 4;
        float4 a4 = *(const float4*)&tq[d];
        float4 b4 = *(const float4*)&hk[d];
        s += a4.x * b4.x + a4.y * b4.y + a4.z * b4.z + a4.w * b4.w;
      }
      s += __shfl_xor(s, 1); s += __shfl_xor(s, 2);
      if (p == 0) scl[w][qk] = s * 0.0625f;
    }
    __syncthreads();

    // ---- B3: softmax ----
    if (tid < 32) {
      int b = tid >> 2, q = tid & 3;
      float s0 = scl[b][q * 4 + 0], s1 = scl[b][q * 4 + 1];
      float s2 = scl[b][q * 4 + 2], s3 = scl[b][q * 4 + 3];
      float mx = fmaxf(fmaxf(s0, s1), fmaxf(s2, s3));
      float e0 = __expf(s0 - mx), e1 = __expf(s1 - mx);
      float e2 = __expf(s2 - mx), e3 = __expf(s3 - mx);
      float inv = 1.f / (e0 + e1 + e2 + e3);
      attn[b][q][0] = e0 * inv; attn[b][q][1] = e1 * inv;
      attn[b][q][2] = e2 * inv; attn[b][q][3] = e3 * inv;
    }
    __syncthreads();

    // ---- B4: e -> A-frags (registers) -> MFMA z_rec ----
    {
      int q = w >> 1, mh = w & 1;
      int row = l & 15, kg = l >> 4;
      int s0 = (t - 1) & 3, s1 = (t - 2) & 3, s2 = (t - 3) & 3, s3 = (t - 4) & 3;
      f32x4 acc0 = {0.f, 0.f, 0.f, 0.f}, acc1 = {0.f, 0.f, 0.f, 0.f};
#pragma unroll
      for (int f = 0; f < 4; ++f) {
        float ev[8];
        if (row < 8) {
          int m0 = mh * 128 + f * 32 + kg * 8;
          float a0 = attn[row][q][0], a1 = attn[row][q][1];
          float a2 = attn[row][q][2], a3 = attn[row][q][3];
          const float* v0 = &vring[RIDX(s0, row, m0)];
          const float* v1 = &vring[RIDX(s1, row, m0)];
          const float* v2 = &vring[RIDX(s2, row, m0)];
          const float* v3 = &vring[RIDX(s3, row, m0)];
#pragma unroll
          for (int j = 0; j < 8; ++j)
            ev[j] = a0 * v0[j] + a1 * v1[j] + a2 * v2[j] + a3 * v3[j];
        } else {
#pragma unroll
          for (int j = 0; j < 8; ++j) ev[j] = 0.f;
        }
        bf16x8 af;
#pragma unroll
        for (int j = 0; j < 8; ++j) af[j] = (__bf16)ev[j];
        acc0 = __builtin_amdgcn_mfma_f32_16x16x32_bf16(af, bfrag[f][0], acc0, 0, 0, 0);
        acc1 = __builtin_amdgcn_mfma_f32_16x16x32_bf16(af, bfrag[f][1], acc1, 0, 0, 0);
      }
      *(f32x4*)&zsc[w][l][0] = acc0;
      *(f32x4*)&zsc[w][l][4] = acc1;
    }
    __syncthreads();

    // ---- B5: combine z (K-split reduce) ----
    if (tid < 256) {
      int lane = ((cb >> 2) << 4) + (cn & 15);
      int idx = ((cn >> 4) << 2) + (cb & 3);
      float z = zxv + bsl[cn >> 3][cn & 7];
#pragma unroll
      for (int ww = 0; ww < 8; ++ww) z += zsc[ww][lane][idx];
      zf[cb][cn] = z;
    }
    __syncthreads();

    // ---- B6: gates + state + publish ----
    if (tid < 64) {
      int b = tid >> 3, uu = tid & 7;
      float fg = sigf(zf[b][uu]);
      float ig = sigf(zf[b][8 + uu]);
      float og = sigf(zf[b][16 + uu]);
      float ch = tanhf(zf[b][24 + uu]);
      creg = fmaf(fg, creg, ig * ch);
      float h = og * tanhf(creg);
      int gb = grp * 8 + b;
      Hg[(gb << 8) + uo0 + uu] = h;
      out[((size_t)gb * 1024 + t) * 256 + uo0 + uu] = h;
    }
    xbar(flg, go, us, 2 * t + 2);  // ---- sync B ----
  }
}

extern "C" void kernel_launch(void* const* d_in, const int* in_sizes, int n_in,
                              void* d_out, int out_size, void* d_ws, size_t ws_size,
                              hipStream_t stream) {
  const float* x = (const float*)d_in[0];
  const float* ker = (const float*)d_in[1];
  const float* ra = (const float*)d_in[2];
  const float* bias = (const float*)d_in[3];
  const float* wq = (const float*)d_in[4];
  const float* wk = (const float*)d_in[5];
  const float* wv = (const float*)d_in[6];
  float* out = (float*)d_out;

  char* ws = (char*)d_ws;
  unsigned* bar = (unsigned*)ws;                 // flags[8][32] @0, go[8] @2048
  float* Hg = (float*)(ws + 4096);               // 64 KB
  float* Tg = (float*)(ws + 4096 + 65536);       // 64 KB
  float* Vg = (float*)(ws + 4096 + 131072);      // 64 KB
  float* S = (float*)(ws + 4096 + 196608);       // 256 KB
  const size_t ZOFF = 1u << 20;
  float* zxf = (float*)(ws + ZOFF);
  __hip_bfloat16* zxh = (__hip_bfloat16*)(ws + ZOFF);

  bool zx32 = (ws_size >= ZOFF + (size_t)B_ * T_ * 4 * U_ * 4);

  hipMemsetAsync(ws, 0, 4096 + 196608, stream);  // bar + Hg/Tg/Vg
  k_S<<<256, 256, 0, stream>>>(wq, wk, S);
  if (zx32) {
    k_zx<true><<<dim3(1024, 2, 4), 256, 0, stream>>>(x, ker, zxf, zxh);
    k_loop<true><<<256, 512, 0, stream>>>(S, ra, wv, zxf, zxh, bias, out, Hg, Tg, Vg, bar);
  } else {
    k_zx<false><<<dim3(1024, 2, 4), 256, 0, stream>>>(x, ker, zxf, zxh);
    k_loop<false><<<256, 512, 0, stream>>>(S, ra, wv, zxf, zxh, bias, out, Hg, Tg, Vg, bar);
  }
}